// Round 2
// baseline (643.013 us; speedup 1.0000x reference)
//
#include <hip/hip_runtime.h>

#define N_CODES 512
#define D 32
#define NVEC (8192 * 64)          // 524288 vectors
#define ZQ_ELEMS (NVEC * D)       // 16777216
#define MARGIN 3e-5f

// ws layout: [0..7] double loss accumulator; [64..2111] float c32[512]

__global__ void vq_prep(const float* __restrict__ cb, float* __restrict__ c32,
                        double* __restrict__ acc) {
    int n = threadIdx.x;                 // 512 threads, 1 block
    if (n == 0) *acc = 0.0;
    double s = 0.0;
#pragma unroll
    for (int d = 0; d < D; ++d) {
        double w = (double)cb[n * D + d];
        s = fma(w, w, s);
    }
    c32[n] = (float)s;                   // platonic ||w||^2 rounded once to f32
}

__global__ __launch_bounds__(256) void vq_main(
        const float* __restrict__ z, const float* __restrict__ cb,
        const float* __restrict__ c32, float* __restrict__ zq_out,
        float* __restrict__ idx_out, double* __restrict__ acc) {
    const int v = blockIdx.x * blockDim.x + threadIdx.x;  // 0..NVEC-1

    // z vector into registers (8 x float4)
    float zr[D];
    const float4* zp = (const float4*)(z + (size_t)v * D);
#pragma unroll
    for (int i = 0; i < D / 4; ++i) {
        float4 t = zp[i];
        zr[4 * i + 0] = t.x; zr[4 * i + 1] = t.y;
        zr[4 * i + 2] = t.z; zr[4 * i + 3] = t.w;
    }

    // platonic A = ||z||^2 (f64 accumulate, single rounding to f32)
    double Ad = 0.0;
#pragma unroll
    for (int d = 0; d < D; ++d) Ad = fma((double)zr[d], (double)zr[d], Ad);
    const float Af = (float)Ad;

    // Pass 1: fast f32 score  s = ||w||^2 - 2 z.w  (offset-free)
    float m1 = 1e30f, m2 = 1e30f;
    int i1 = 0;
    for (int n = 0; n < N_CODES; ++n) {
        const float* w = cb + n * D;   // wave-uniform address -> scalar loads
        float dot = 0.f;
#pragma unroll
        for (int d = 0; d < D; ++d) dot = fmaf(zr[d], w[d], dot);
        float s = fmaf(-2.f, dot, c32[n]);
        float hi = fmaxf(s, m1);
        m2 = fminf(m2, hi);
        bool c = s < m1;
        i1 = c ? n : i1;
        m1 = fminf(m1, s);
    }

    int winner = i1;
    // Pass 2: near-tie under f32 quantization of the reference formula.
    // Emulate dists = f32(f32(A - 2B) + C) with platonic (f64->f32) A,B,C;
    // argmin with strict < == first-index tie-break (matches np/jnp argmin).
    if (m2 - m1 <= MARGIN) {
        float best_d = 1e30f;
        int best_i = 0;
        for (int n = 0; n < N_CODES; ++n) {
            const float* w = cb + n * D;
            float dot = 0.f;
#pragma unroll
            for (int d = 0; d < D; ++d) dot = fmaf(zr[d], w[d], dot);
            float s = fmaf(-2.f, dot, c32[n]);
            if (s <= m1 + MARGIN) {
                double bd = 0.0;
#pragma unroll
                for (int d = 0; d < D; ++d)
                    bd = fma((double)zr[d], (double)w[d], bd);
                float B32 = (float)bd;                      // platonic dot
                float dq = __fadd_rn(__fsub_rn(Af, __fmul_rn(2.0f, B32)),
                                     c32[n]);               // ref association
                if (dq < best_d) { best_d = dq; best_i = n; }
            }
        }
        winner = best_i;
    }

    // gather z_q, write outputs, accumulate loss
    const float4* q = (const float4*)(cb + (size_t)winner * D);
    float4* o = (float4*)(zq_out + (size_t)v * D);
    float ss = 0.f;
#pragma unroll
    for (int i = 0; i < D / 4; ++i) {
        float4 t = q[i];
        o[i] = t;
        float d0 = zr[4 * i + 0] - t.x;
        float d1 = zr[4 * i + 1] - t.y;
        float d2 = zr[4 * i + 2] - t.z;
        float d3 = zr[4 * i + 3] - t.w;
        ss = fmaf(d0, d0, fmaf(d1, d1, fmaf(d2, d2, fmaf(d3, d3, ss))));
    }
    idx_out[v] = (float)winner;

    double dss = (double)ss;
#pragma unroll
    for (int off = 32; off > 0; off >>= 1) dss += __shfl_down(dss, off, 64);
    if ((threadIdx.x & 63) == 0) atomicAdd(acc, dss);
}

__global__ void vq_final(const double* __restrict__ acc,
                         float* __restrict__ loss_out) {
    *loss_out = (float)(1.25 * (*acc) / (double)ZQ_ELEMS);
}

extern "C" void kernel_launch(void* const* d_in, const int* in_sizes, int n_in,
                              void* d_out, int out_size, void* d_ws, size_t ws_size,
                              hipStream_t stream) {
    const float* z  = (const float*)d_in[0];
    const float* cb = (const float*)d_in[1];
    float* out  = (float*)d_out;
    float* zq   = out;
    float* idxo = out + ZQ_ELEMS;
    float* loss = out + ZQ_ELEMS + NVEC;
    double* acc = (double*)d_ws;
    float* c32  = (float*)((char*)d_ws + 64);

    vq_prep<<<1, N_CODES, 0, stream>>>(cb, c32, acc);
    vq_main<<<NVEC / 256, 256, 0, stream>>>(z, cb, c32, zq, idxo, acc);
    vq_final<<<1, 1, 0, stream>>>(acc, loss);
}